// Round 9
// baseline (165.134 us; speedup 1.0000x reference)
//
#include <hip/hip_runtime.h>
#include <hip/hip_bf16.h>
#include <stdint.h>

// Problem sizes (fixed by reference)
#define BT     8
#define T_SEQ  4096
#define K_F    512
#define N_H    1024
#define M_TOT  (BT * T_SEQ)   // 32768
#define NLAYER 4
#define LC     32             // chunk length for parallel scan
#define NC     (T_SEQ / LC)   // 128 chunks

typedef short  bf16x8 __attribute__((ext_vector_type(8)));
typedef float  f32x4  __attribute__((ext_vector_type(4)));
typedef ushort u16x8  __attribute__((ext_vector_type(8)));
typedef ushort u16x4  __attribute__((ext_vector_type(4)));

// f32 -> bf16 (round-to-nearest-even)
__device__ __forceinline__ ushort f2bf(float f) {
  uint32_t u = __builtin_bit_cast(uint32_t, f);
  u += 0x7fffu + ((u >> 16) & 1u);
  return (ushort)(u >> 16);
}
__device__ __forceinline__ float bf2f(ushort u) {
  uint32_t x = (uint32_t)u << 16;
  return __builtin_bit_cast(float, x);
}

// async global->LDS, 16B per lane (global_load_lds_dwordx4).
__device__ __forceinline__ void gload16(const void* g, void* l) {
  __builtin_amdgcn_global_load_lds(
      (const __attribute__((address_space(1))) uint32_t*)g,
      (__attribute__((address_space(3))) uint32_t*)l, 16, 0, 0);
}

// ---------------- prep: W [K][N] f32 -> Wt [N][K] bf16 ----------------
__global__ __launch_bounds__(256) void prep_w_kernel(const float* __restrict__ W,
                                                     ushort* __restrict__ Wt) {
  __shared__ float tile[32][33];
  const int k0 = (blockIdx.x & 15) * 32;   // 16 K tiles
  const int n0 = (blockIdx.x >> 4) * 32;   // 32 N tiles
  const int lx = threadIdx.x & 31;
  const int ly = threadIdx.x >> 5;
#pragma unroll
  for (int j = 0; j < 32; j += 8)
    tile[ly + j][lx] = W[(size_t)(k0 + ly + j) * N_H + n0 + lx];
  __syncthreads();
#pragma unroll
  for (int j = 0; j < 32; j += 8)
    Wt[(size_t)(n0 + ly + j) * K_F + k0 + lx] = f2bf(tile[lx][ly + j]);
}

// ---------------- persistent-A GEMM + fused chunk-state -------------------
// One block per 128-row M-tile (grid 256 = 1 block/CU). 512 threads, 8 waves
// (2M x 4N -> per-wave 64x32 per N-tile). LDS 160 KiB:
//   lsA [128][512] bf16 (128K) -- A resident full-K, staged ONCE from f32 x
//       with in-register conversion; frag reads XOR-swizzled ((row&7)<<3).
//   lsB [2][128][64] bf16 (32K) -- B K-tile double buffer via global_load_lds.
// K-loop schedule = proven minimal 2-phase (race-free; R8 post-mortem):
//   per kt: { STAGE(kt+1 -> buf^1); ds_read frags(buf); MFMA; __syncthreads(); }
// __syncthreads supplies vmcnt(0)+lgkmcnt(0)+barrier+fence: reads of buf^1
// are drained BEFORE the next iteration's stage targets it. B is L2-resident
// (1 MiB), so its ~250cy latency hides under the ds_read+MFMA phase.
// Per-N-tile epilogue reuses lsB as the 128x128 bf16 output tile: coalesced
// Yb stores + fused chunk-state (4 chunks x 128 h = 512 tasks, 1/thread).
__global__ __launch_bounds__(512) void gemm_fused(
    const float* __restrict__ x, const ushort* __restrict__ Wt,
    const float* __restrict__ bias, ushort* __restrict__ Yb,
    const float* __restrict__ As, const float* __restrict__ Bs,
    const float* __restrict__ Cs, const float* __restrict__ Ds,
    float* __restrict__ E) {
  __shared__ ushort lsA[128 * 512];      // 128 KiB
  __shared__ ushort lsB[2][128 * 64];    // 32 KiB (also epilogue tile)
  ushort* tile = &lsB[0][0];

  const int tid  = threadIdx.x;
  const int lane = tid & 63;
  const int wv   = tid >> 6;     // 0..7
  const int wr   = wv >> 2;      // 0..1 -> 64-row half
  const int wc   = wv & 3;       // 0..3 -> 32-col quarter
  const int m0   = blockIdx.x * 128;
  const int lr   = lane & 15;
  const int kg   = (lane >> 4) * 8;
  const int aswz = (lane & 7) << 3;      // A-read swizzle: (row&7)<<3 == (lr&7)<<3

  // ---- prologue: stage A (f32 -> bf16, swizzled store) + B(n=0,k=0) ----
  {
    const float4* xs = (const float4*)(x + (size_t)m0 * K_F);
#pragma unroll
    for (int j = 0; j < 32; j++) {
      const int e4  = j * 512 + tid;        // f32x4 index, 16384 total
      float4 v = xs[e4];
      const int row = e4 >> 7;              // 128 f32x4 per row
      const int ek4 = (e4 & 127) * 4;       // k-elem offset in row
      u16x4 o;
      o[0] = f2bf(v.x); o[1] = f2bf(v.y); o[2] = f2bf(v.z); o[3] = f2bf(v.w);
      *(u16x4*)&lsA[row * 512 + (ek4 ^ ((row & 7) << 3))] = o;
    }
#pragma unroll
    for (int i = 0; i < 2; i++) {           // B(n=0, k=0) -> lsB[0]
      const int reg = wv * 2 + i;           // 16 regions x 1KB
      gload16(Wt + (size_t)(reg * 8 + (lane >> 3)) * K_F + (lane & 7) * 8,
              &lsB[0][reg * 512]);
    }
  }
  __syncthreads();   // A + B(0,0) resident

  for (int nt = 0; nt < 8; nt++) {
    const int n0 = nt * 128;
    const ushort* WtN = Wt + (size_t)n0 * K_F + (lane & 7) * 8;

    f32x4 acc[4][2];
#pragma unroll
    for (int fm = 0; fm < 4; fm++)
#pragma unroll
      for (int fn = 0; fn < 2; fn++) acc[fm][fn] = (f32x4)0.0f;

#pragma unroll
    for (int kt = 0; kt < 8; kt++) {
      // stage next K-tile into the other buffer (reads of it drained at the
      // previous iteration's __syncthreads -> no write-after-read race)
      if (kt < 7) {
#pragma unroll
        for (int i = 0; i < 2; i++) {
          const int reg = wv * 2 + i;
          gload16(WtN + (size_t)(reg * 8 + (lane >> 3)) * K_F + (kt + 1) * 64,
                  &lsB[(kt + 1) & 1][reg * 512]);
        }
      }

      const ushort* lb = &lsB[kt & 1][0];
      bf16x8 af[4][2], bfr[2][2];
#pragma unroll
      for (int fn = 0; fn < 2; fn++)
#pragma unroll
        for (int kk = 0; kk < 2; kk++)
          bfr[fn][kk] = *(const bf16x8*)&lb[(wc * 32 + fn * 16 + lr) * 64 + kk * 32 + kg];
#pragma unroll
      for (int fm = 0; fm < 4; fm++) {
        const int row = wr * 64 + fm * 16 + lr;
#pragma unroll
        for (int kk = 0; kk < 2; kk++)
          af[fm][kk] = *(const bf16x8*)&lsA[row * 512 + ((kt * 64 + kk * 32 + kg) ^ aswz)];
      }
#pragma unroll
      for (int kk = 0; kk < 2; kk++)
#pragma unroll
        for (int fm = 0; fm < 4; fm++)
#pragma unroll
          for (int fn = 0; fn < 2; fn++)
            acc[fm][fn] = __builtin_amdgcn_mfma_f32_16x16x32_bf16(af[fm][kk], bfr[fn][kk],
                                                                  acc[fm][fn], 0, 0, 0);
      __syncthreads();   // drain vmcnt (stage landed) + lgkm; full fence
    }
    // all reads of lsB done -> safe to use as epilogue tile

    // ---- epilogue 1: acc -> tile [128 t][128 h] bf16 (+bias) ----
#pragma unroll
    for (int fn = 0; fn < 2; fn++) {
      const int col = wc * 32 + fn * 16 + lr;
      const float bv = bias[n0 + col];
#pragma unroll
      for (int fm = 0; fm < 4; fm++) {
        const int row0 = wr * 64 + fm * 16 + (lane >> 4) * 4;
#pragma unroll
        for (int i = 0; i < 4; i++)
          tile[(row0 + i) * 128 + col] = f2bf(acc[fm][fn][i] + bv);
      }
    }
    __syncthreads();

    // ---- epilogue 2a: coalesced Yb store (256B rows) ----
    {
      const int erow = tid >> 4;            // 0..31
      const int ecol = (tid & 15) * 8;
#pragma unroll
      for (int p = 0; p < 4; p++) {
        const int row = p * 32 + erow;
        *(u16x8*)&Yb[(size_t)(m0 + row) * N_H + n0 + ecol] =
            *(const u16x8*)&tile[row * 128 + ecol];
      }
    }
    // ---- epilogue 2b: fused chunk-state (bit-identical to standalone) ----
    {
      const int ck = tid >> 7;              // chunk in tile, 0..3
      const int hl = tid & 127;
      const int h  = n0 + hl;
      float a[4], bb[4], cc[4], dd[4];
#pragma unroll
      for (int l = 0; l < 4; l++) {
        a[l]  = 1.f / (1.f + __expf(-As[l * N_H + h]));
        bb[l] = Bs[l * N_H + h];
        cc[l] = Cs[l * N_H + h];
        dd[l] = Ds[l * N_H + h];
      }
      float s[4] = {0.f, 0.f, 0.f, 0.f};
#pragma unroll 4
      for (int t = 0; t < LC; t++) {
        float xv = bf2f(tile[(ck * LC + t) * 128 + hl]);
#pragma unroll
        for (int l = 0; l < 4; l++) {
          s[l] = fmaf(a[l], s[l], bb[l] * xv);
          xv = fmaf(cc[l], s[l], dd[l]);
        }
      }
      const int bidx = m0 >> 12;                 // batch
      const int c0   = (m0 & (T_SEQ - 1)) >> 5;  // first chunk of tile
      f32x4 e;
      e[0] = s[0]; e[1] = s[1]; e[2] = s[2]; e[3] = s[3];
      ((f32x4*)E)[(size_t)(bidx * NC + c0 + ck) * N_H + h] = e;
    }
    __syncthreads();   // all tile reads drained before restaging lsB[0]

    if (nt < 7) {      // stage B(nt+1, k=0) into lsB[0]
#pragma unroll
      for (int i = 0; i < 2; i++) {
        const int reg = wv * 2 + i;
        gload16(Wt + (size_t)((nt + 1) * 128 + reg * 8 + (lane >> 3)) * K_F + (lane & 7) * 8,
                &lsB[0][reg * 512]);
      }
      __syncthreads();  // drain the k0 stage before kt=0 reads it
    }
  }
}

// ============ chunked parallel scan (passes B and C) ============
// Pass B: per-(b,h) serial combine over chunks with P=M^LC -> start states S.
__global__ __launch_bounds__(256) void chunk_scan_kernel(
    const float* __restrict__ A, const float* __restrict__ B,
    const float* __restrict__ C, const float* __restrict__ E,
    float* __restrict__ S) {
  const int idx = blockIdx.x * 256 + threadIdx.x;
  const int b = idx >> 10;
  const int h = idx & (N_H - 1);

  float a[4], bcoef[4], ccoef[4];
#pragma unroll
  for (int l = 0; l < 4; l++) {
    a[l] = 1.f / (1.f + __expf(-A[l * N_H + h]));
    bcoef[l] = B[l * N_H + h];
    ccoef[l] = C[l * N_H + h];
  }

  float m[4][4] = {};
  m[0][0] = a[0];
  m[1][0] = bcoef[1] * ccoef[0] * a[0];
  m[1][1] = a[1];
  m[2][0] = bcoef[2] * ccoef[1] * m[1][0];
  m[2][1] = bcoef[2] * ccoef[1] * a[1];
  m[2][2] = a[2];
  m[3][0] = bcoef[3] * ccoef[2] * m[2][0];
  m[3][1] = bcoef[3] * ccoef[2] * m[2][1];
  m[3][2] = bcoef[3] * ccoef[2] * a[2];
  m[3][3] = a[3];

  // P = M^LC, LC=32 -> 5 squarings
#pragma unroll
  for (int it = 0; it < 5; it++) {
    float t[4][4];
#pragma unroll
    for (int i = 0; i < 4; i++)
#pragma unroll
      for (int j = 0; j < 4; j++) {
        float acc = 0.f;
#pragma unroll
        for (int k = 0; k < 4; k++) acc = fmaf(m[i][k], m[k][j], acc);
        t[i][j] = acc;
      }
#pragma unroll
    for (int i = 0; i < 4; i++)
#pragma unroll
      for (int j = 0; j < 4; j++) m[i][j] = t[i][j];
  }

  float s[4] = {0.f, 0.f, 0.f, 0.f};
  const f32x4* Ep = (const f32x4*)E + (size_t)b * NC * N_H + h;
  f32x4* Sp = (f32x4*)S + (size_t)b * NC * N_H + h;
#pragma unroll 4
  for (int c = 0; c < NC; c++) {
    f32x4 sv;
    sv[0] = s[0]; sv[1] = s[1]; sv[2] = s[2]; sv[3] = s[3];
    Sp[(size_t)c * N_H] = sv;
    f32x4 e = Ep[(size_t)c * N_H];
    float ns[4];
#pragma unroll
    for (int i = 0; i < 4; i++) {
      float acc = e[i];
#pragma unroll
      for (int k = 0; k < 4; k++) acc = fmaf(m[i][k], s[k], acc);
      ns[i] = acc;
    }
#pragma unroll
    for (int i = 0; i < 4; i++) s[i] = ns[i];
  }
}

// Pass C: recurrence from exact start state; reads bf16 Y, writes f32 out
__global__ __launch_bounds__(256) void chunk_apply_kernel(
    const ushort* __restrict__ Yb, float* __restrict__ out,
    const float* __restrict__ A, const float* __restrict__ B,
    const float* __restrict__ C, const float* __restrict__ D,
    const float* __restrict__ S) {
  const int b  = blockIdx.x / NC;
  const int c  = blockIdx.x % NC;
  const int h4 = threadIdx.x << 2;

  float a[4][4], bb[4][4], cc[4][4], dd[4][4];
#pragma unroll
  for (int l = 0; l < 4; l++) {
    f32x4 av = *(const f32x4*)(A + l * N_H + h4);
    f32x4 bv = *(const f32x4*)(B + l * N_H + h4);
    f32x4 cv = *(const f32x4*)(C + l * N_H + h4);
    f32x4 dv = *(const f32x4*)(D + l * N_H + h4);
#pragma unroll
    for (int ch = 0; ch < 4; ch++) {
      a[l][ch]  = 1.f / (1.f + __expf(-av[ch]));
      bb[l][ch] = bv[ch]; cc[l][ch] = cv[ch]; dd[l][ch] = dv[ch];
    }
  }

  float s[4][4];
  const f32x4* sp = (const f32x4*)S + (size_t)(b * NC + c) * N_H + h4;
#pragma unroll
  for (int ch = 0; ch < 4; ch++) {
    f32x4 sv = sp[ch];
    s[0][ch] = sv[0]; s[1][ch] = sv[1]; s[2][ch] = sv[2]; s[3][ch] = sv[3];
  }

  const ushort* ybase = Yb + ((size_t)b * T_SEQ + (size_t)c * LC) * N_H + h4;
  f32x4* op = (f32x4*)(out + ((size_t)b * T_SEQ + (size_t)c * LC) * N_H) + (h4 >> 2);
#pragma unroll 4
  for (int t = 0; t < LC; t++) {
    u16x4 xv = *(const u16x4*)(ybase + (size_t)t * N_H);
    f32x4 ov;
#pragma unroll
    for (int ch = 0; ch < 4; ch++) {
      float x = bf2f(xv[ch]);
#pragma unroll
      for (int l = 0; l < 4; l++) {
        s[l][ch] = fmaf(a[l][ch], s[l][ch], bb[l][ch] * x);
        x = fmaf(cc[l][ch], s[l][ch], dd[l][ch]);
      }
      ov[ch] = x;
    }
    op[(size_t)t * (N_H / 4)] = ov;
  }
}

extern "C" void kernel_launch(void* const* d_in, const int* in_sizes, int n_in,
                              void* d_out, int out_size, void* d_ws, size_t ws_size,
                              hipStream_t stream) {
  const float* x    = (const float*)d_in[0];
  const float* W    = (const float*)d_in[1];
  const float* b_in = (const float*)d_in[2];
  const float* A    = (const float*)d_in[3];
  const float* B    = (const float*)d_in[4];
  const float* C    = (const float*)d_in[5];
  const float* bias = (const float*)d_in[6];
  float* out = (float*)d_out;

  // ws layout (512 MiB available):
  //   Wt  [0,    1 MiB)  bf16 W^T
  //   Yb  [8,   72 MiB)  bf16 intermediate Y
  //   E   [112, 128 MiB) f32 chunk end states
  //   S   [128, 144 MiB) f32 chunk start states
  char* wsb = (char*)d_ws;
  ushort* Wt = (ushort*)wsb;
  ushort* Yb = (ushort*)(wsb + (size_t)8 * 1024 * 1024);
  float*  E  = (float*)(wsb + (size_t)112 * 1024 * 1024);
  float*  S  = E + (size_t)BT * NC * N_H * 4;

  prep_w_kernel<<<512, 256, 0, stream>>>(W, Wt);
  gemm_fused<<<M_TOT / 128, 512, 0, stream>>>(x, Wt, b_in, Yb, A, B, C, bias, E);
  chunk_scan_kernel<<<(BT * N_H) / 256, 256, 0, stream>>>(A, B, C, E, S);
  chunk_apply_kernel<<<BT * NC, 256, 0, stream>>>(Yb, out, A, B, C, bias, S);
}